// Round 1
// baseline (3438.607 us; speedup 1.0000x reference)
//
#include <hip/hip_runtime.h>
#include <math.h>

#define Bq 4
#define Sq 2048
#define DMq 1024
#define Hq 16
#define Dq 64
#define CAPf 15.0f
#define EPSf 1e-6f

// ---------------- RMSNorm ----------------
// one block per (b,s) row; 256 threads x float4 = 1024 elems
__global__ void rmsnorm_kernel(const float* __restrict__ x,
                               const float* __restrict__ ln_w,
                               float* __restrict__ xn) {
    int row = blockIdx.x;
    const float4* xr = (const float4*)(x + (size_t)row * DMq);
    float4* xo = (float4*)(xn + (size_t)row * DMq);
    int tid = threadIdx.x;
    float4 v = xr[tid];
    float ss = v.x*v.x + v.y*v.y + v.z*v.z + v.w*v.w;
    #pragma unroll
    for (int off = 32; off > 0; off >>= 1) ss += __shfl_down(ss, off);
    __shared__ float red[4];
    int lane = tid & 63, wv = tid >> 6;
    if (lane == 0) red[wv] = ss;
    __syncthreads();
    float tot = red[0] + red[1] + red[2] + red[3];
    float rs = rsqrtf(tot * (1.0f / DMq) + EPSf);
    float4 w4 = ((const float4*)ln_w)[tid];
    float4 o;
    o.x = v.x * rs * w4.x;
    o.y = v.y * rs * w4.y;
    o.z = v.z * rs * w4.z;
    o.w = v.w * rs * w4.w;
    xo[tid] = o;
}

// ---------------- fp32 tiled GEMM: C[M,N] = A[M,K] @ B[N,K]^T (+resid) ----------------
// 64x64 tile, BK=16, 256 threads, 4x4 micro-tile per thread. M % 64 == 0 assumed.
template<bool RESID>
__global__ __launch_bounds__(256) void gemm_nt(const float* __restrict__ A,
                                               const float* __restrict__ Bw,
                                               const float* __restrict__ resid,
                                               float* __restrict__ C,
                                               int M, int N, int K) {
    __shared__ float As[16][64];
    __shared__ float Bs[16][64];
    int bm = blockIdx.y * 64;
    int bn = blockIdx.x * 64;
    int tid = threadIdx.x;
    int tm = tid >> 4;          // 0..15 (row group)
    int tn = tid & 15;          // 0..15 (col group)
    int lr = tid >> 2;          // 0..63 tile row for loading
    int lc = (tid & 3) << 2;    // 0,4,8,12 k-offset for loading
    float acc[4][4] = {{0.f}};

    for (int k0 = 0; k0 < K; k0 += 16) {
        float4 a4 = *(const float4*)(A + (size_t)(bm + lr) * K + k0 + lc);
        float4 b4 = make_float4(0.f, 0.f, 0.f, 0.f);
        int brow = bn + lr;
        if (brow < N) b4 = *(const float4*)(Bw + (size_t)brow * K + k0 + lc);
        __syncthreads();
        As[lc + 0][lr] = a4.x; As[lc + 1][lr] = a4.y;
        As[lc + 2][lr] = a4.z; As[lc + 3][lr] = a4.w;
        Bs[lc + 0][lr] = b4.x; Bs[lc + 1][lr] = b4.y;
        Bs[lc + 2][lr] = b4.z; Bs[lc + 3][lr] = b4.w;
        __syncthreads();
        #pragma unroll
        for (int k = 0; k < 16; k++) {
            float4 av = *(const float4*)&As[k][tm << 2];
            float4 bv = *(const float4*)&Bs[k][tn << 2];
            acc[0][0] += av.x * bv.x; acc[0][1] += av.x * bv.y;
            acc[0][2] += av.x * bv.z; acc[0][3] += av.x * bv.w;
            acc[1][0] += av.y * bv.x; acc[1][1] += av.y * bv.y;
            acc[1][2] += av.y * bv.z; acc[1][3] += av.y * bv.w;
            acc[2][0] += av.z * bv.x; acc[2][1] += av.z * bv.y;
            acc[2][2] += av.z * bv.z; acc[2][3] += av.z * bv.w;
            acc[3][0] += av.w * bv.x; acc[3][1] += av.w * bv.y;
            acc[3][2] += av.w * bv.z; acc[3][3] += av.w * bv.w;
        }
    }
    #pragma unroll
    for (int i = 0; i < 4; i++) {
        int row = bm + (tm << 2) + i;
        #pragma unroll
        for (int j = 0; j < 4; j++) {
            int col = bn + (tn << 2) + j;
            if (col < N) {
                size_t idx = (size_t)row * N + col;
                float v = acc[i][j];
                if (RESID) v += resid[idx];
                C[idx] = v;
            }
        }
    }
}

// ---------------- gate activation: sigmoid(CAP * tanh(g / CAP)) ----------------
__global__ void gate_act_kernel(float* __restrict__ g, int n) {
    int i = blockIdx.x * blockDim.x + threadIdx.x;
    if (i < n) {
        float v = g[i];
        v = CAPf * tanhf(v * (1.0f / CAPf));
        g[i] = 1.0f / (1.0f + expf(-v));
    }
}

// ---------------- recurrence scan ----------------
// grid = B*H blocks, 64 threads (1 wave). lane e owns state column h[0..63][e] in regs.
__global__ __launch_bounds__(64) void scan_kernel(const float* __restrict__ qkv,
                                                  const float* __restrict__ gates,
                                                  const float* __restrict__ h0,
                                                  float* __restrict__ att,
                                                  float* __restrict__ hfin) {
    int bh = blockIdx.x;
    int b = bh >> 4, hh = bh & 15;
    int e = threadIdx.x;

    float h[Dq];
    #pragma unroll
    for (int d = 0; d < Dq; d++)
        h[d] = h0[(((size_t)b * Hq + hh) * Dq + d) * Dq + e];

    for (int s = 0; s < Sq; s++) {
        size_t rowoff = (size_t)(b * Sq + s) * (3 * Hq * Dq);
        const float* qp = qkv + rowoff + hh * Dq;
        const float* kp = qkv + rowoff + (Hq + hh) * Dq;
        const float* vp = qkv + rowoff + (2 * Hq + hh) * Dq;
        const float* gp = gates + (size_t)(b * Sq + s) * (3 * Hq);
        float ig = gp[hh], fg = gp[Hq + hh], og = gp[2 * Hq + hh];
        float ve = vp[e];
        float ikv = ig * ve;
        float acc = 0.f;
        #pragma unroll
        for (int d = 0; d < Dq; d++) {
            h[d] = fg * h[d] + ikv * kp[d];
            acc += qp[d] * h[d];
        }
        att[(size_t)(b * Sq + s) * (Hq * Dq) + hh * Dq + e] = og * acc;
    }
    #pragma unroll
    for (int d = 0; d < Dq; d++)
        hfin[(((size_t)b * Hq + hh) * Dq + d) * Dq + e] = h[d];
}

extern "C" void kernel_launch(void* const* d_in, const int* in_sizes, int n_in,
                              void* d_out, int out_size, void* d_ws, size_t ws_size,
                              hipStream_t stream) {
    const float* x      = (const float*)d_in[0];
    const float* h0     = (const float*)d_in[1];
    const float* w_qkv  = (const float*)d_in[2];
    const float* w_gate = (const float*)d_in[3];
    const float* w_out  = (const float*)d_in[4];
    const float* ln_w   = (const float*)d_in[5];

    const size_t MS   = (size_t)Bq * Sq;          // 8192 rows
    const size_t xn_e   = MS * DMq;               // 8.4M
    const size_t qkv_e  = MS * 3 * Hq * Dq;       // 25.2M
    const size_t gate_e = MS * 3 * Hq;            // 0.39M
    const size_t att_e  = MS * Hq * Dq;           // 8.4M
    size_t need = (xn_e + qkv_e + gate_e + att_e) * sizeof(float);
    if (ws_size < need) return;  // workspace insufficient -> will show as validation failure

    float* xn    = (float*)d_ws;
    float* qkv   = xn + xn_e;
    float* gates = qkv + qkv_e;
    float* att   = gates + gate_e;

    float* y    = (float*)d_out;                  // B*S*DM
    float* hfin = y + (size_t)Bq * Sq * DMq;      // B*H*D*D

    // 1. RMSNorm
    rmsnorm_kernel<<<dim3(MS), dim3(256), 0, stream>>>(x, ln_w, xn);

    // 2. QKV GEMM: (8192 x 1024) @ (3072 x 1024)^T
    gemm_nt<false><<<dim3(3 * Hq * Dq / 64, MS / 64), dim3(256), 0, stream>>>(
        xn, w_qkv, nullptr, qkv, (int)MS, 3 * Hq * Dq, DMq);

    // 3. Gates GEMM: (8192 x 1024) @ (48 x 1024)^T
    gemm_nt<false><<<dim3(1, MS / 64), dim3(256), 0, stream>>>(
        xn, w_gate, nullptr, gates, (int)MS, 3 * Hq, DMq);

    // 4. gate activation
    gate_act_kernel<<<dim3((gate_e + 255) / 256), dim3(256), 0, stream>>>(gates, (int)gate_e);

    // 5. recurrence scan
    scan_kernel<<<dim3(Bq * Hq), dim3(64), 0, stream>>>(qkv, gates, h0, att, hfin);

    // 6. output GEMM + residual: y = x + att @ w_out^T
    gemm_nt<true><<<dim3(DMq / 64, MS / 64), dim3(256), 0, stream>>>(
        att, w_out, x, y, (int)MS, DMq, Hq * Dq);
}

// Round 2
// 1234.835 us; speedup vs baseline: 2.7847x; 2.7847x over previous
//
#include <hip/hip_runtime.h>
#include <math.h>

#define Bq 4
#define Sq 2048
#define DMq 1024
#define Hq 16
#define Dq 64
#define CAPf 15.0f
#define EPSf 1e-6f
#define Tc 64
#define Cc (Sq / Tc)   // 32 chunks

// ---------------- RMSNorm ----------------
__global__ void rmsnorm_kernel(const float* __restrict__ x,
                               const float* __restrict__ ln_w,
                               float* __restrict__ xn) {
    int row = blockIdx.x;
    const float4* xr = (const float4*)(x + (size_t)row * DMq);
    float4* xo = (float4*)(xn + (size_t)row * DMq);
    int tid = threadIdx.x;
    float4 v = xr[tid];
    float ss = v.x*v.x + v.y*v.y + v.z*v.z + v.w*v.w;
    #pragma unroll
    for (int off = 32; off > 0; off >>= 1) ss += __shfl_down(ss, off);
    __shared__ float red[4];
    int lane = tid & 63, wv = tid >> 6;
    if (lane == 0) red[wv] = ss;
    __syncthreads();
    float tot = red[0] + red[1] + red[2] + red[3];
    float rs = rsqrtf(tot * (1.0f / DMq) + EPSf);
    float4 w4 = ((const float4*)ln_w)[tid];
    float4 o;
    o.x = v.x * rs * w4.x;
    o.y = v.y * rs * w4.y;
    o.z = v.z * rs * w4.z;
    o.w = v.w * rs * w4.w;
    xo[tid] = o;
}

// ---------------- fp32 tiled GEMM: C[M,N] = A[M,K] @ B[N,K]^T (+resid) ----------------
template<bool RESID>
__global__ __launch_bounds__(256) void gemm_nt(const float* __restrict__ A,
                                               const float* __restrict__ Bw,
                                               const float* __restrict__ resid,
                                               float* __restrict__ C,
                                               int M, int N, int K) {
    __shared__ float As[16][64];
    __shared__ float Bs[16][64];
    int bm = blockIdx.y * 64;
    int bn = blockIdx.x * 64;
    int tid = threadIdx.x;
    int tm = tid >> 4;
    int tn = tid & 15;
    int lr = tid >> 2;
    int lc = (tid & 3) << 2;
    float acc[4][4] = {{0.f}};

    for (int k0 = 0; k0 < K; k0 += 16) {
        float4 a4 = *(const float4*)(A + (size_t)(bm + lr) * K + k0 + lc);
        float4 b4 = make_float4(0.f, 0.f, 0.f, 0.f);
        int brow = bn + lr;
        if (brow < N) b4 = *(const float4*)(Bw + (size_t)brow * K + k0 + lc);
        __syncthreads();
        As[lc + 0][lr] = a4.x; As[lc + 1][lr] = a4.y;
        As[lc + 2][lr] = a4.z; As[lc + 3][lr] = a4.w;
        Bs[lc + 0][lr] = b4.x; Bs[lc + 1][lr] = b4.y;
        Bs[lc + 2][lr] = b4.z; Bs[lc + 3][lr] = b4.w;
        __syncthreads();
        #pragma unroll
        for (int k = 0; k < 16; k++) {
            float4 av = *(const float4*)&As[k][tm << 2];
            float4 bv = *(const float4*)&Bs[k][tn << 2];
            acc[0][0] += av.x * bv.x; acc[0][1] += av.x * bv.y;
            acc[0][2] += av.x * bv.z; acc[0][3] += av.x * bv.w;
            acc[1][0] += av.y * bv.x; acc[1][1] += av.y * bv.y;
            acc[1][2] += av.y * bv.z; acc[1][3] += av.y * bv.w;
            acc[2][0] += av.z * bv.x; acc[2][1] += av.z * bv.y;
            acc[2][2] += av.z * bv.z; acc[2][3] += av.z * bv.w;
            acc[3][0] += av.w * bv.x; acc[3][1] += av.w * bv.y;
            acc[3][2] += av.w * bv.z; acc[3][3] += av.w * bv.w;
        }
    }
    #pragma unroll
    for (int i = 0; i < 4; i++) {
        int row = bm + (tm << 2) + i;
        #pragma unroll
        for (int j = 0; j < 4; j++) {
            int col = bn + (tn << 2) + j;
            if (col < N) {
                size_t idx = (size_t)row * N + col;
                float v = acc[i][j];
                if (RESID) v += resid[idx];
                C[idx] = v;
            }
        }
    }
}

// ---------------- gate activation ----------------
__global__ void gate_act_kernel(float* __restrict__ g, int n) {
    int i = blockIdx.x * blockDim.x + threadIdx.x;
    if (i < n) {
        float v = g[i];
        v = CAPf * tanhf(v * (1.0f / CAPf));
        g[i] = 1.0f / (1.0f + expf(-v));
    }
}

// ---------------- pass1: per-chunk local scan ----------------
// grid = B*H*Cc blocks, 64 threads. lane e owns state column h[0..63][e].
// Outputs: att (local part), Acum[b,s,h] (within-chunk cumulative decay incl. step),
//          Fchunk[bh,c] (chunk total decay), Lmat[bh,c,d,e] (chunk-final local state).
__global__ __launch_bounds__(64) void scan_pass1(const float* __restrict__ qkv,
                                                 const float* __restrict__ gates,
                                                 const float* __restrict__ h0,
                                                 float* __restrict__ att,
                                                 float* __restrict__ Lmat,
                                                 float* __restrict__ Acum,
                                                 float* __restrict__ Fchunk) {
    int blk = blockIdx.x;
    int c = blk & (Cc - 1);
    int bh = blk >> 5;            // /Cc
    int b = bh >> 4, hh = bh & 15;
    int e = threadIdx.x;

    __shared__ float qs[2][64], ks[2][64];

    float h[Dq];
    if (c == 0) {
        #pragma unroll
        for (int d = 0; d < Dq; d++)
            h[d] = h0[((size_t)bh * Dq + d) * Dq + e];
    } else {
        #pragma unroll
        for (int d = 0; d < Dq; d++) h[d] = 0.f;
    }

    int s0 = c * Tc;
    // prefetch step s0
    size_t ro = (size_t)(b * Sq + s0) * (3 * Hq * Dq);
    float qe = qkv[ro + hh * Dq + e];
    float ke = qkv[ro + (Hq + hh) * Dq + e];
    float ve = qkv[ro + (2 * Hq + hh) * Dq + e];
    const float* gp = gates + (size_t)(b * Sq + s0) * (3 * Hq);
    float ig = gp[hh], fg = gp[Hq + hh], og = gp[2 * Hq + hh];

    float cumf = 1.f;
    for (int t = 0; t < Tc; t++) {
        int s = s0 + t;
        int buf = t & 1;
        qs[buf][e] = qe;
        ks[buf][e] = ke;
        float vcur = ve, igc = ig, fgc = fg, ogc = og;
        if (t + 1 < Tc) {   // prefetch next step
            size_t ro2 = (size_t)(b * Sq + s + 1) * (3 * Hq * Dq);
            qe = qkv[ro2 + hh * Dq + e];
            ke = qkv[ro2 + (Hq + hh) * Dq + e];
            ve = qkv[ro2 + (2 * Hq + hh) * Dq + e];
            const float* gp2 = gates + (size_t)(b * Sq + s + 1) * (3 * Hq);
            ig = gp2[hh]; fg = gp2[Hq + hh]; og = gp2[2 * Hq + hh];
        }
        __syncthreads();
        cumf *= fgc;
        float ikv = igc * vcur;
        float acc = 0.f;
        #pragma unroll
        for (int d0 = 0; d0 < Dq; d0 += 4) {
            float4 k4 = *(const float4*)&ks[buf][d0];
            float4 q4 = *(const float4*)&qs[buf][d0];
            h[d0+0] = fgc*h[d0+0] + ikv*k4.x; acc += q4.x*h[d0+0];
            h[d0+1] = fgc*h[d0+1] + ikv*k4.y; acc += q4.y*h[d0+1];
            h[d0+2] = fgc*h[d0+2] + ikv*k4.z; acc += q4.z*h[d0+2];
            h[d0+3] = fgc*h[d0+3] + ikv*k4.w; acc += q4.w*h[d0+3];
        }
        att[(size_t)(b * Sq + s) * (Hq * Dq) + hh * Dq + e] = ogc * acc;
        if (e == 0) Acum[(size_t)(b * Sq + s) * Hq + hh] = cumf;
    }
    #pragma unroll
    for (int d = 0; d < Dq; d++)
        Lmat[((size_t)bh * Cc + c) * (Dq * Dq) + d * Dq + e] = h[d];
    if (e == 0) Fchunk[bh * Cc + c] = cumf;
}

// ---------------- pass2: cross-chunk combine (elementwise over b,h,d,e) ----------------
// In-place: LH[bh,c,:] is L_c on entry, Hstart_c on exit. Writes hfin.
__global__ __launch_bounds__(256) void scan_pass2(float* __restrict__ LH,
                                                  const float* __restrict__ Fchunk,
                                                  float* __restrict__ hfin) {
    int idx = blockIdx.x * 256 + threadIdx.x;   // over BH*4096
    int bh = idx >> 12;
    int de = idx & 4095;
    float run = 0.f;
    #pragma unroll
    for (int c = 0; c < Cc; c++) {
        float Fv = Fchunk[bh * Cc + c];
        size_t off = ((size_t)bh * Cc + c) * (Dq * Dq) + de;
        float Lv = LH[off];
        LH[off] = run;          // Hstart_c
        run = Fv * run + Lv;
    }
    hfin[idx] = run;
}

// ---------------- pass3: add cross-chunk contribution ----------------
// att[s] += og * A_t * (q_t . Hstart_c). Chunk 0 skipped (Hstart = 0).
__global__ __launch_bounds__(64) void scan_pass3(const float* __restrict__ qkv,
                                                 const float* __restrict__ gates,
                                                 const float* __restrict__ Hstart,
                                                 const float* __restrict__ Acum,
                                                 float* __restrict__ att) {
    int blk = blockIdx.x;
    int c = 1 + (blk % (Cc - 1));
    int bh = blk / (Cc - 1);
    int b = bh >> 4, hh = bh & 15;
    int e = threadIdx.x;

    __shared__ float qs[2][64];

    float h[Dq];
    #pragma unroll
    for (int d = 0; d < Dq; d++)
        h[d] = Hstart[((size_t)bh * Cc + c) * (Dq * Dq) + d * Dq + e];

    int s0 = c * Tc;
    size_t ro = (size_t)(b * Sq + s0) * (3 * Hq * Dq);
    float qe = qkv[ro + hh * Dq + e];
    float og = gates[(size_t)(b * Sq + s0) * (3 * Hq) + 2 * Hq + hh];
    float Av = Acum[(size_t)(b * Sq + s0) * Hq + hh];

    for (int t = 0; t < Tc; t++) {
        int s = s0 + t;
        int buf = t & 1;
        qs[buf][e] = qe;
        float ogc = og, Ac = Av;
        if (t + 1 < Tc) {
            size_t ro2 = (size_t)(b * Sq + s + 1) * (3 * Hq * Dq);
            qe = qkv[ro2 + hh * Dq + e];
            og = gates[(size_t)(b * Sq + s + 1) * (3 * Hq) + 2 * Hq + hh];
            Av = Acum[(size_t)(b * Sq + s + 1) * Hq + hh];
        }
        __syncthreads();
        float acc = 0.f;
        #pragma unroll
        for (int d0 = 0; d0 < Dq; d0 += 4) {
            float4 q4 = *(const float4*)&qs[buf][d0];
            acc += q4.x*h[d0+0] + q4.y*h[d0+1] + q4.z*h[d0+2] + q4.w*h[d0+3];
        }
        size_t oi = (size_t)(b * Sq + s) * (Hq * Dq) + hh * Dq + e;
        att[oi] += ogc * Ac * acc;
    }
}

extern "C" void kernel_launch(void* const* d_in, const int* in_sizes, int n_in,
                              void* d_out, int out_size, void* d_ws, size_t ws_size,
                              hipStream_t stream) {
    const float* x      = (const float*)d_in[0];
    const float* h0     = (const float*)d_in[1];
    const float* w_qkv  = (const float*)d_in[2];
    const float* w_gate = (const float*)d_in[3];
    const float* w_out  = (const float*)d_in[4];
    const float* ln_w   = (const float*)d_in[5];

    const size_t MS     = (size_t)Bq * Sq;        // 8192 rows
    const size_t xn_e   = MS * DMq;               // 8.39M (reused as Lmat/Hstart)
    const size_t qkv_e  = MS * 3 * Hq * Dq;       // 25.2M
    const size_t gate_e = MS * 3 * Hq;            // 0.39M
    const size_t att_e  = MS * Hq * Dq;           // 8.39M
    const size_t acum_e = MS * Hq;                // 131072
    const size_t fch_e  = (size_t)Bq * Hq * Cc;   // 2048
    size_t need = (xn_e + qkv_e + gate_e + att_e + acum_e + fch_e) * sizeof(float);
    if (ws_size < need) return;

    float* xn    = (float*)d_ws;      // dead after gates GEMM; reused as Lmat/Hstart
    float* qkv   = xn + xn_e;
    float* gates = qkv + qkv_e;
    float* att   = gates + gate_e;
    float* Acum  = att + att_e;
    float* Fch   = Acum + acum_e;
    float* Lmat  = xn;

    float* y    = (float*)d_out;
    float* hfin = y + (size_t)Bq * Sq * DMq;

    rmsnorm_kernel<<<dim3(MS), dim3(256), 0, stream>>>(x, ln_w, xn);

    gemm_nt<false><<<dim3(3 * Hq * Dq / 64, MS / 64), dim3(256), 0, stream>>>(
        xn, w_qkv, nullptr, qkv, (int)MS, 3 * Hq * Dq, DMq);

    gemm_nt<false><<<dim3(1, MS / 64), dim3(256), 0, stream>>>(
        xn, w_gate, nullptr, gates, (int)MS, 3 * Hq, DMq);

    gate_act_kernel<<<dim3((gate_e + 255) / 256), dim3(256), 0, stream>>>(gates, (int)gate_e);

    scan_pass1<<<dim3(Bq * Hq * Cc), dim3(64), 0, stream>>>(qkv, gates, h0, att, Lmat, Acum, Fch);
    scan_pass2<<<dim3(Bq * Hq * Dq * Dq / 256), dim3(256), 0, stream>>>(Lmat, Fch, hfin);
    scan_pass3<<<dim3(Bq * Hq * (Cc - 1)), dim3(64), 0, stream>>>(qkv, gates, Lmat, Acum, att);

    gemm_nt<true><<<dim3(DMq / 64, MS / 64), dim3(256), 0, stream>>>(
        att, w_out, x, y, (int)MS, DMq, Hq * Dq);
}

// Round 3
// 281.396 us; speedup vs baseline: 12.2198x; 4.3883x over previous
//
#include <hip/hip_runtime.h>
#include <hip/hip_bf16.h>
#include <math.h>

#define Bq 4
#define Sq 2048
#define DMq 1024
#define Hq 16
#define Dq 64
#define CAPf 15.0f
#define EPSf 1e-6f
#define Tc 64
#define Cc (Sq / Tc)   // 32 chunks

typedef __attribute__((ext_vector_type(8))) short short8;
typedef __attribute__((ext_vector_type(4))) float f32x4;
typedef __hip_bfloat16 bf16;

__device__ __forceinline__ float b2f(bf16 v) { return __bfloat162float(v); }
__device__ __forceinline__ bf16  f2b(float v) { return __float2bfloat16(v); }

// ---------------- fp32 -> bf16 convert (4 elems/thread) ----------------
__global__ void convert_f32_bf16(const float* __restrict__ in, bf16* __restrict__ out, int n4) {
    int i = blockIdx.x * 256 + threadIdx.x;
    if (i < n4) {
        float4 v = ((const float4*)in)[i];
        bf16 t[4] = {f2b(v.x), f2b(v.y), f2b(v.z), f2b(v.w)};
        ((uint2*)out)[i] = *(uint2*)t;
    }
}

// ---------------- RMSNorm -> bf16 ----------------
__global__ void rmsnorm_kernel(const float* __restrict__ x,
                               const float* __restrict__ ln_w,
                               bf16* __restrict__ xn) {
    int row = blockIdx.x;
    const float4* xr = (const float4*)(x + (size_t)row * DMq);
    int tid = threadIdx.x;
    float4 v = xr[tid];
    float ss = v.x*v.x + v.y*v.y + v.z*v.z + v.w*v.w;
    #pragma unroll
    for (int off = 32; off > 0; off >>= 1) ss += __shfl_down(ss, off);
    __shared__ float red[4];
    int lane = tid & 63, wv = tid >> 6;
    if (lane == 0) red[wv] = ss;
    __syncthreads();
    float tot = red[0] + red[1] + red[2] + red[3];
    float rs = rsqrtf(tot * (1.0f / DMq) + EPSf);
    float4 w4 = ((const float4*)ln_w)[tid];
    bf16 t[4] = {f2b(v.x * rs * w4.x), f2b(v.y * rs * w4.y),
                 f2b(v.z * rs * w4.z), f2b(v.w * rs * w4.w)};
    *(uint2*)(xn + (size_t)row * DMq + tid * 4) = *(uint2*)t;
}

// ---------------- bf16 MFMA GEMM: C[M,N] = A[M,K] @ B[N,K]^T ----------------
// 128x128 tile, BK=64, 256 threads = 4 waves (2x2), each wave 64x64 = 4x4 frags
// of 16x16x32. LDS XOR-swizzled ([row][slot^(row&7)] 16B slots) so both the
// global_load_lds linear write and the frag ds_read_b128 are canonical
// (8 lanes per bank-quad). Source address pre-swizzled per rule #21.
enum Epi { EPI_NONE = 0, EPI_GATE = 1, EPI_RESID = 2 };

template<int EPI>
__global__ __launch_bounds__(256) void gemm_mfma(const bf16* __restrict__ A,
                                                 const bf16* __restrict__ Bw,
                                                 const float* __restrict__ resid,
                                                 float* __restrict__ C,
                                                 int M, int N, int K) {
    __shared__ bf16 As[128 * 64];
    __shared__ bf16 Bs[128 * 64];
    const int tid = threadIdx.x;
    const int w = tid >> 6;            // wave 0..3
    const int l = tid & 63;
    const int wr = (w >> 1) * 64;      // wave row offset in tile
    const int wc = (w & 1) * 64;       // wave col offset in tile
    const int bm = blockIdx.y * 128;
    const int bn = blockIdx.x * 128;

    // staging: each wave fills 32 rows of each tile with 4 global_load_lds.
    const int lrow = l >> 3;                   // 0..7 row within 8-row group
    const int swzc = ((l & 7) ^ lrow) * 8;     // pre-swizzled k-offset (elems)

    // frag-read constants
    const int fl = l & 15;
    const int kb = l >> 4;                     // k-block 0..3
    const int rsw = l & 7;                     // frag row & 7

    f32x4 acc[4][4];
    #pragma unroll
    for (int i = 0; i < 4; i++)
        #pragma unroll
        for (int j = 0; j < 4; j++) acc[i][j] = (f32x4){0.f, 0.f, 0.f, 0.f};

    for (int k0 = 0; k0 < K; k0 += 64) {
        __syncthreads();
        #pragma unroll
        for (int inst = 0; inst < 4; inst++) {
            int r0 = w * 32 + inst * 8;
            const bf16* gp = A + (size_t)(bm + r0 + lrow) * K + k0 + swzc;
            __builtin_amdgcn_global_load_lds(
                (const __attribute__((address_space(1))) uint32_t*)gp,
                (__attribute__((address_space(3))) uint32_t*)(As + r0 * 64),
                16, 0, 0);
        }
        #pragma unroll
        for (int inst = 0; inst < 4; inst++) {
            int r0 = w * 32 + inst * 8;
            if (bn + r0 < N) {   // whole-instruction guard (N multiple of 8)
                const bf16* gp = Bw + (size_t)(bn + r0 + lrow) * K + k0 + swzc;
                __builtin_amdgcn_global_load_lds(
                    (const __attribute__((address_space(1))) uint32_t*)gp,
                    (__attribute__((address_space(3))) uint32_t*)(Bs + r0 * 64),
                    16, 0, 0);
            }
        }
        __syncthreads();
        #pragma unroll
        for (int kk2 = 0; kk2 < 2; kk2++) {
            const int koff = (((kk2 << 2) + kb) ^ rsw) * 8;  // swizzled 16B slot
            short8 af[4], bfr[4];
            #pragma unroll
            for (int i = 0; i < 4; i++)
                af[i] = *(const short8*)(As + (wr + i * 16 + fl) * 64 + koff);
            #pragma unroll
            for (int j = 0; j < 4; j++)
                bfr[j] = *(const short8*)(Bs + (wc + j * 16 + fl) * 64 + koff);
            #pragma unroll
            for (int i = 0; i < 4; i++)
                #pragma unroll
                for (int j = 0; j < 4; j++)
                    acc[i][j] = __builtin_amdgcn_mfma_f32_16x16x32_bf16(
                        af[i], bfr[j], acc[i][j], 0, 0, 0);
        }
    }

    // epilogue: C[row][col], row = (l>>4)*4 + r, col = l&15 within frag
    #pragma unroll
    for (int i = 0; i < 4; i++) {
        #pragma unroll
        for (int j = 0; j < 4; j++) {
            int col = bn + wc + j * 16 + fl;
            if (EPI == EPI_GATE && col >= N) continue;
            #pragma unroll
            for (int r = 0; r < 4; r++) {
                int row = bm + wr + i * 16 + kb * 4 + r;
                size_t idx = (size_t)row * N + col;
                float v = acc[i][j][r];
                if (EPI == EPI_GATE) {
                    v = CAPf * tanhf(v * (1.0f / CAPf));
                    v = 1.0f / (1.0f + expf(-v));
                }
                if (EPI == EPI_RESID) v += resid[idx];
                C[idx] = v;
            }
        }
    }
}

// ---------------- pass1: per-chunk local scan ----------------
__global__ __launch_bounds__(64) void scan_pass1(const float* __restrict__ qkv,
                                                 const float* __restrict__ gates,
                                                 const float* __restrict__ h0,
                                                 bf16* __restrict__ attb,
                                                 bf16* __restrict__ Lb,
                                                 float* __restrict__ Acum,
                                                 float* __restrict__ Fchunk) {
    int blk = blockIdx.x;
    int c = blk & (Cc - 1);
    int bh = blk >> 5;
    int b = bh >> 4, hh = bh & 15;
    int e = threadIdx.x;

    __shared__ float qs[2][64], ks[2][64];

    float h[Dq];
    if (c == 0) {
        #pragma unroll
        for (int d = 0; d < Dq; d++)
            h[d] = h0[((size_t)bh * Dq + d) * Dq + e];
    } else {
        #pragma unroll
        for (int d = 0; d < Dq; d++) h[d] = 0.f;
    }

    int s0 = c * Tc;
    size_t ro = (size_t)(b * Sq + s0) * (3 * Hq * Dq);
    float qe = qkv[ro + hh * Dq + e];
    float ke = qkv[ro + (Hq + hh) * Dq + e];
    float ve = qkv[ro + (2 * Hq + hh) * Dq + e];
    const float* gp = gates + (size_t)(b * Sq + s0) * (3 * Hq);
    float ig = gp[hh], fg = gp[Hq + hh], og = gp[2 * Hq + hh];

    float cumf = 1.f;
    for (int t = 0; t < Tc; t++) {
        int s = s0 + t;
        int buf = t & 1;
        qs[buf][e] = qe;
        ks[buf][e] = ke;
        float vcur = ve, igc = ig, fgc = fg, ogc = og;
        if (t + 1 < Tc) {
            size_t ro2 = (size_t)(b * Sq + s + 1) * (3 * Hq * Dq);
            qe = qkv[ro2 + hh * Dq + e];
            ke = qkv[ro2 + (Hq + hh) * Dq + e];
            ve = qkv[ro2 + (2 * Hq + hh) * Dq + e];
            const float* gp2 = gates + (size_t)(b * Sq + s + 1) * (3 * Hq);
            ig = gp2[hh]; fg = gp2[Hq + hh]; og = gp2[2 * Hq + hh];
        }
        __syncthreads();
        cumf *= fgc;
        float ikv = igc * vcur;
        float acc = 0.f;
        #pragma unroll
        for (int d0 = 0; d0 < Dq; d0 += 4) {
            float4 k4 = *(const float4*)&ks[buf][d0];
            float4 q4 = *(const float4*)&qs[buf][d0];
            h[d0+0] = fgc*h[d0+0] + ikv*k4.x; acc += q4.x*h[d0+0];
            h[d0+1] = fgc*h[d0+1] + ikv*k4.y; acc += q4.y*h[d0+1];
            h[d0+2] = fgc*h[d0+2] + ikv*k4.z; acc += q4.z*h[d0+2];
            h[d0+3] = fgc*h[d0+3] + ikv*k4.w; acc += q4.w*h[d0+3];
        }
        attb[(size_t)(b * Sq + s) * (Hq * Dq) + hh * Dq + e] = f2b(ogc * acc);
        if (e == 0) Acum[(size_t)(b * Sq + s) * Hq + hh] = cumf;
    }
    #pragma unroll
    for (int d = 0; d < Dq; d++)
        Lb[((size_t)bh * Cc + c) * (Dq * Dq) + d * Dq + e] = f2b(h[d]);
    if (e == 0) Fchunk[bh * Cc + c] = cumf;
}

// ---------------- pass2: cross-chunk combine ----------------
__global__ __launch_bounds__(256) void scan_pass2(bf16* __restrict__ LH,
                                                  const float* __restrict__ Fchunk,
                                                  float* __restrict__ hfin) {
    int idx = blockIdx.x * 256 + threadIdx.x;   // over BH*4096
    int bh = idx >> 12;
    int de = idx & 4095;
    float run = 0.f;
    #pragma unroll
    for (int c = 0; c < Cc; c++) {
        float Fv = Fchunk[bh * Cc + c];
        size_t off = ((size_t)bh * Cc + c) * (Dq * Dq) + de;
        float Lv = b2f(LH[off]);
        LH[off] = f2b(run);      // Hstart_c
        run = Fv * run + Lv;
    }
    hfin[idx] = run;
}

// ---------------- pass3: add cross-chunk contribution ----------------
__global__ __launch_bounds__(64) void scan_pass3(const float* __restrict__ qkv,
                                                 const float* __restrict__ gates,
                                                 const bf16* __restrict__ Hstart,
                                                 const float* __restrict__ Acum,
                                                 bf16* __restrict__ attb) {
    int blk = blockIdx.x;
    int c = 1 + (blk % (Cc - 1));
    int bh = blk / (Cc - 1);
    int b = bh >> 4, hh = bh & 15;
    int e = threadIdx.x;

    __shared__ float qs[2][64];

    float h[Dq];
    #pragma unroll
    for (int d = 0; d < Dq; d++)
        h[d] = b2f(Hstart[((size_t)bh * Cc + c) * (Dq * Dq) + d * Dq + e]);

    int s0 = c * Tc;
    size_t ro = (size_t)(b * Sq + s0) * (3 * Hq * Dq);
    float qe = qkv[ro + hh * Dq + e];
    float og = gates[(size_t)(b * Sq + s0) * (3 * Hq) + 2 * Hq + hh];
    float Av = Acum[(size_t)(b * Sq + s0) * Hq + hh];

    for (int t = 0; t < Tc; t++) {
        int s = s0 + t;
        int buf = t & 1;
        qs[buf][e] = qe;
        float ogc = og, Ac = Av;
        if (t + 1 < Tc) {
            size_t ro2 = (size_t)(b * Sq + s + 1) * (3 * Hq * Dq);
            qe = qkv[ro2 + hh * Dq + e];
            og = gates[(size_t)(b * Sq + s + 1) * (3 * Hq) + 2 * Hq + hh];
            Av = Acum[(size_t)(b * Sq + s + 1) * Hq + hh];
        }
        __syncthreads();
        float acc = 0.f;
        #pragma unroll
        for (int d0 = 0; d0 < Dq; d0 += 4) {
            float4 q4 = *(const float4*)&qs[buf][d0];
            acc += q4.x*h[d0+0] + q4.y*h[d0+1] + q4.z*h[d0+2] + q4.w*h[d0+3];
        }
        size_t oi = (size_t)(b * Sq + s) * (Hq * Dq) + hh * Dq + e;
        attb[oi] = f2b(b2f(attb[oi]) + ogc * Ac * acc);
    }
}

extern "C" void kernel_launch(void* const* d_in, const int* in_sizes, int n_in,
                              void* d_out, int out_size, void* d_ws, size_t ws_size,
                              hipStream_t stream) {
    const float* x      = (const float*)d_in[0];
    const float* h0     = (const float*)d_in[1];
    const float* w_qkv  = (const float*)d_in[2];
    const float* w_gate = (const float*)d_in[3];
    const float* w_out  = (const float*)d_in[4];
    const float* ln_w   = (const float*)d_in[5];

    const size_t MS = (size_t)Bq * Sq;            // 8192

    // workspace layout (f32 slots); xnb is reused as attb (dead after GEMMs)
    float* p = (float*)d_ws;
    bf16*  xnb   = (bf16*)p;  p += MS * DMq / 2;                 // 4,194,304
    float* qkv   = p;         p += MS * 3 * Hq * Dq;             // 25,165,824
    float* gates = p;         p += MS * 3 * Hq;                  // 393,216
    float* Acum  = p;         p += MS * Hq;                      // 131,072
    float* Fch   = p;         p += (size_t)Bq * Hq * Cc;         // 2,048
    bf16*  Lb    = (bf16*)p;  p += (size_t)Bq * Hq * Cc * Dq * Dq / 2; // 4,194,304
    bf16*  wqb   = (bf16*)p;  p += (size_t)3 * Hq * Dq * DMq / 2;      // 1,572,864
    bf16*  wgb   = (bf16*)p;  p += (size_t)3 * Hq * DMq / 2;           // 24,576
    bf16*  wob   = (bf16*)p;  p += (size_t)DMq * Hq * Dq / 2;          // 524,288
    size_t need = (size_t)(p - (float*)d_ws) * sizeof(float);
    if (ws_size < need) return;
    bf16* attb = xnb;   // alias: xnb dead after QKV+gates GEMMs

    float* y    = (float*)d_out;
    float* hfin = y + MS * DMq;

    // weight conversions (n4 = elems/4)
    convert_f32_bf16<<<dim3(3072), dim3(256), 0, stream>>>(w_qkv, wqb, 3 * Hq * Dq * DMq / 4);
    convert_f32_bf16<<<dim3(48),   dim3(256), 0, stream>>>(w_gate, wgb, 3 * Hq * DMq / 4);
    convert_f32_bf16<<<dim3(1024), dim3(256), 0, stream>>>(w_out, wob, DMq * Hq * Dq / 4);

    rmsnorm_kernel<<<dim3(MS), dim3(256), 0, stream>>>(x, ln_w, xnb);

    // QKV: (8192x1024)bf16 @ (3072x1024)^T -> f32
    gemm_mfma<EPI_NONE><<<dim3(3 * Hq * Dq / 128, MS / 128), dim3(256), 0, stream>>>(
        xnb, wqb, nullptr, qkv, (int)MS, 3 * Hq * Dq, DMq);

    // gates: (8192x1024)bf16 @ (48x1024)^T -> sigmoid(cap-tanh) f32
    gemm_mfma<EPI_GATE><<<dim3(1, MS / 128), dim3(256), 0, stream>>>(
        xnb, wgb, nullptr, gates, (int)MS, 3 * Hq, DMq);

    scan_pass1<<<dim3(Bq * Hq * Cc), dim3(64), 0, stream>>>(qkv, gates, h0, attb, Lb, Acum, Fch);
    scan_pass2<<<dim3(Bq * Hq * Dq * Dq / 256), dim3(256), 0, stream>>>(Lb, Fch, hfin);
    scan_pass3<<<dim3(Bq * Hq * (Cc - 1)), dim3(64), 0, stream>>>(qkv, gates, Lb, Acum, attb);

    // out: (8192x1024)bf16 @ (1024x1024)^T + x -> f32
    gemm_mfma<EPI_RESID><<<dim3(DMq / 128, MS / 128), dim3(256), 0, stream>>>(
        attb, wob, x, y, (int)MS, DMq, Hq * Dq);
}

// Round 4
// 177.139 us; speedup vs baseline: 19.4120x; 1.5886x over previous
//
#include <hip/hip_runtime.h>
#include <hip/hip_bf16.h>
#include <math.h>
#include <stdint.h>

#define Bq 4
#define Sq 2048
#define DMq 1024
#define Hq 16
#define Dq 64
#define CAPf 15.0f
#define EPSf 1e-6f
#define Tc 64
#define Cc (Sq / Tc)   // 32 chunks
#define QKVW (3 * Hq * Dq)   // 3072

typedef __attribute__((ext_vector_type(8))) short short8;
typedef __attribute__((ext_vector_type(4))) float f32x4;
typedef __hip_bfloat16 bf16;

__device__ __forceinline__ float b2f(bf16 v) { return __bfloat162float(v); }
__device__ __forceinline__ bf16  f2b(float v) { return __float2bfloat16(v); }
__device__ __forceinline__ uint16_t f2bu(float f) {
    bf16 h = __float2bfloat16(f); uint16_t u; __builtin_memcpy(&u, &h, 2); return u;
}
__device__ __forceinline__ float bu2f(uint16_t u) {
    uint32_t x = ((uint32_t)u) << 16; float f; __builtin_memcpy(&f, &x, 4); return f;
}

// ---------------- fp32 -> bf16 convert ----------------
__global__ void convert_f32_bf16(const float* __restrict__ in, bf16* __restrict__ out, int n4) {
    int i = blockIdx.x * 256 + threadIdx.x;
    if (i < n4) {
        float4 v = ((const float4*)in)[i];
        bf16 t[4] = {f2b(v.x), f2b(v.y), f2b(v.z), f2b(v.w)};
        ((uint2*)out)[i] = *(uint2*)t;
    }
}

// ---------------- RMSNorm -> bf16 ----------------
__global__ void rmsnorm_kernel(const float* __restrict__ x,
                               const float* __restrict__ ln_w,
                               bf16* __restrict__ xn) {
    int row = blockIdx.x;
    const float4* xr = (const float4*)(x + (size_t)row * DMq);
    int tid = threadIdx.x;
    float4 v = xr[tid];
    float ss = v.x*v.x + v.y*v.y + v.z*v.z + v.w*v.w;
    #pragma unroll
    for (int off = 32; off > 0; off >>= 1) ss += __shfl_down(ss, off);
    __shared__ float red[4];
    int lane = tid & 63, wv = tid >> 6;
    if (lane == 0) red[wv] = ss;
    __syncthreads();
    float tot = red[0] + red[1] + red[2] + red[3];
    float rs = rsqrtf(tot * (1.0f / DMq) + EPSf);
    float4 w4 = ((const float4*)ln_w)[tid];
    bf16 t[4] = {f2b(v.x * rs * w4.x), f2b(v.y * rs * w4.y),
                 f2b(v.z * rs * w4.z), f2b(v.w * rs * w4.w)};
    *(uint2*)(xn + (size_t)row * DMq + tid * 4) = *(uint2*)t;
}

// ---------------- bf16 MFMA GEMM: C[M,N] = A[M,K] @ B[N,K]^T ----------------
enum Epi { EPI_BF16 = 0, EPI_GATE = 1, EPI_RESID = 2 };

template<int EPI>
__global__ __launch_bounds__(256) void gemm_mfma(const bf16* __restrict__ A,
                                                 const bf16* __restrict__ Bw,
                                                 const float* __restrict__ resid,
                                                 void* __restrict__ Cv,
                                                 int M, int N, int K) {
    __shared__ bf16 As[128 * 64];
    __shared__ bf16 Bs[128 * 64];
    const int tid = threadIdx.x;
    const int w = tid >> 6;
    const int l = tid & 63;
    const int wr = (w >> 1) * 64;
    const int wc = (w & 1) * 64;
    const int bm = blockIdx.y * 128;
    const int bn = blockIdx.x * 128;

    const int lrow = l >> 3;
    const int swzc = ((l & 7) ^ lrow) * 8;

    const int fl = l & 15;
    const int kb = l >> 4;
    const int rsw = l & 7;

    f32x4 acc[4][4];
    #pragma unroll
    for (int i = 0; i < 4; i++)
        #pragma unroll
        for (int j = 0; j < 4; j++) acc[i][j] = (f32x4){0.f, 0.f, 0.f, 0.f};

    for (int k0 = 0; k0 < K; k0 += 64) {
        __syncthreads();
        #pragma unroll
        for (int inst = 0; inst < 4; inst++) {
            int r0 = w * 32 + inst * 8;
            const bf16* gp = A + (size_t)(bm + r0 + lrow) * K + k0 + swzc;
            __builtin_amdgcn_global_load_lds(
                (const __attribute__((address_space(1))) uint32_t*)gp,
                (__attribute__((address_space(3))) uint32_t*)(As + r0 * 64),
                16, 0, 0);
        }
        #pragma unroll
        for (int inst = 0; inst < 4; inst++) {
            int r0 = w * 32 + inst * 8;
            if (bn + r0 < N) {
                const bf16* gp = Bw + (size_t)(bn + r0 + lrow) * K + k0 + swzc;
                __builtin_amdgcn_global_load_lds(
                    (const __attribute__((address_space(1))) uint32_t*)gp,
                    (__attribute__((address_space(3))) uint32_t*)(Bs + r0 * 64),
                    16, 0, 0);
            }
        }
        __syncthreads();
        #pragma unroll
        for (int kk2 = 0; kk2 < 2; kk2++) {
            const int koff = (((kk2 << 2) + kb) ^ rsw) * 8;
            short8 af[4], bfr[4];
            #pragma unroll
            for (int i = 0; i < 4; i++)
                af[i] = *(const short8*)(As + (wr + i * 16 + fl) * 64 + koff);
            #pragma unroll
            for (int j = 0; j < 4; j++)
                bfr[j] = *(const short8*)(Bs + (wc + j * 16 + fl) * 64 + koff);
            #pragma unroll
            for (int i = 0; i < 4; i++)
                #pragma unroll
                for (int j = 0; j < 4; j++)
                    acc[i][j] = __builtin_amdgcn_mfma_f32_16x16x32_bf16(
                        af[i], bfr[j], acc[i][j], 0, 0, 0);
        }
    }

    #pragma unroll
    for (int i = 0; i < 4; i++) {
        #pragma unroll
        for (int j = 0; j < 4; j++) {
            int col = bn + wc + j * 16 + fl;
            if (EPI == EPI_GATE && col >= N) continue;
            #pragma unroll
            for (int r = 0; r < 4; r++) {
                int row = bm + wr + i * 16 + kb * 4 + r;
                size_t idx = (size_t)row * N + col;
                float v = acc[i][j][r];
                if (EPI == EPI_GATE) {
                    v = CAPf * tanhf(v * (1.0f / CAPf));
                    ((float*)Cv)[idx] = 1.0f / (1.0f + expf(-v));
                } else if (EPI == EPI_RESID) {
                    ((float*)Cv)[idx] = v + resid[idx];
                } else {
                    ((bf16*)Cv)[idx] = f2b(v);
                }
            }
        }
    }
}

// ---------------- chunk kernel A: intra-chunk attention + chunk state ----------------
// 1 wave per (bh, c). out_intra = (QK^T ⊙ D) V, LT[e][d] = sum_j w_j V[j][e] K[j][d].
__global__ __launch_bounds__(64) void chunk_intra(const bf16* __restrict__ qkvb,
                                                  const float* __restrict__ gates,
                                                  bf16* __restrict__ attb,
                                                  bf16* __restrict__ LT,
                                                  float* __restrict__ oaArr,
                                                  float* __restrict__ Fch) {
    const int blk = blockIdx.x;
    const int c  = blk & (Cc - 1);
    const int bh = blk >> 5;
    const int b = bh >> 4, hh = bh & 15;
    const int l = threadIdx.x;
    const int s0 = c * Tc;

    __shared__ bf16 KTs[4096];   // [d][j] w-scaled, XOR-swizzled
    __shared__ bf16 VTs[4096];   // [e][j] swizzled
    __shared__ bf16 Ps[4096];    // [t][j] swizzled
    __shared__ float rowS[64], pcolS[64], wstS[64];

    // gates for step t = lane; log-space cumulative decay scan
    const float* gp = gates + (size_t)(b * Sq + s0 + l) * (3 * Hq);
    float ig = gp[hh], fg = gp[Hq + hh], og = gp[2 * Hq + hh];
    float la = __logf(fg);
    #pragma unroll
    for (int off = 1; off < 64; off <<= 1) {
        float v = __shfl_up(la, off);
        if (l >= off) la += v;
    }
    float la63 = __shfl(la, 63);
    float li = __logf(ig);
    rowS[l]  = la + __logf(og);            // row factor: log(a_t * o_t)
    pcolS[l] = li - la;                    // col factor: log(i_j / a_j)
    wstS[l]  = __expf(la63 - la + li);     // state weight w_j <= 1
    float oa = og * __expf(la);
    oaArr[(size_t)blk * 64 + l] = oa;
    if (l == 0) Fch[blk] = __expf(la63);
    __syncthreads();

    // stage KT (scaled by w_j) and VT, transposed + swizzled
    const int cg = l & 7, rp = l >> 3;
    const size_t rowBase = (size_t)(b * Sq + s0);
    const int kcol = (Hq + hh) * Dq, vcol = (2 * Hq + hh) * Dq;
    #pragma unroll
    for (int pass = 0; pass < 4; pass++) {
        int j0 = pass * 16 + rp * 2;
        const bf16* r0 = qkvb + (rowBase + j0) * QKVW;
        const bf16* r1 = qkvb + (rowBase + j0 + 1) * QKVW;
        short8 k0 = *(const short8*)(r0 + kcol + cg * 8);
        short8 k1 = *(const short8*)(r1 + kcol + cg * 8);
        short8 v0 = *(const short8*)(r0 + vcol + cg * 8);
        short8 v1 = *(const short8*)(r1 + vcol + cg * 8);
        float w0 = wstS[j0], w1 = wstS[j0 + 1];
        #pragma unroll
        for (int s = 0; s < 8; s++) {
            int cc = cg * 8 + s;
            int base = cc * 64 + ((((j0 >> 3) ^ (cc & 7) ^ (cc >> 3))) << 3) + (j0 & 7);
            uint32_t kp = (uint32_t)f2bu(bu2f((uint16_t)k0[s]) * w0)
                        | ((uint32_t)f2bu(bu2f((uint16_t)k1[s]) * w1) << 16);
            uint32_t vp = (uint32_t)(uint16_t)v0[s] | ((uint32_t)(uint16_t)v1[s] << 16);
            *(uint32_t*)&KTs[base] = kp;
            *(uint32_t*)&VTs[base] = vp;
        }
    }

    // S = Q @ K^T from direct global frag loads
    const int fl = l & 15, kb = l >> 4;
    const bf16* Qb = qkvb + rowBase * QKVW + hh * Dq;
    const bf16* Kb = qkvb + rowBase * QKVW + kcol;
    f32x4 accS[4][4];
    #pragma unroll
    for (int i = 0; i < 4; i++)
        #pragma unroll
        for (int j = 0; j < 4; j++) accS[i][j] = (f32x4){0.f, 0.f, 0.f, 0.f};
    #pragma unroll
    for (int ks = 0; ks < 2; ks++) {
        short8 qf[4], kf[4];
        #pragma unroll
        for (int i = 0; i < 4; i++)
            qf[i] = *(const short8*)(Qb + (size_t)(i * 16 + fl) * QKVW + ks * 32 + kb * 8);
        #pragma unroll
        for (int j = 0; j < 4; j++)
            kf[j] = *(const short8*)(Kb + (size_t)(j * 16 + fl) * QKVW + ks * 32 + kb * 8);
        #pragma unroll
        for (int i = 0; i < 4; i++)
            #pragma unroll
            for (int j = 0; j < 4; j++)
                accS[i][j] = __builtin_amdgcn_mfma_f32_16x16x32_bf16(qf[i], kf[j], accS[i][j], 0, 0, 0);
    }

    // P = mask(j<=t) . o_t exp(la_t - la_j + li_j) . S  -> LDS (bf16, swizzled)
    #pragma unroll
    for (int i = 0; i < 4; i++) {
        #pragma unroll
        for (int j = 0; j < 4; j++) {
            int jj = j * 16 + fl;
            float pc = pcolS[jj];
            #pragma unroll
            for (int r = 0; r < 4; r++) {
                int t = i * 16 + kb * 4 + r;
                float p = (jj <= t) ? __expf(rowS[t] + pc) * accS[i][j][r] : 0.f;
                int slot = (jj >> 3) ^ (t & 7) ^ (t >> 3);
                Ps[t * 64 + slot * 8 + (jj & 7)] = f2b(p);
            }
        }
    }
    __syncthreads();

    // out = P @ V  (A=Ps rows t, B=VTs rows e);  LT = VT @ KT^T (A=VTs rows e, B=KTs rows d)
    f32x4 accO[4][4], accL[4][4];
    #pragma unroll
    for (int i = 0; i < 4; i++)
        #pragma unroll
        for (int j = 0; j < 4; j++) {
            accO[i][j] = (f32x4){0.f, 0.f, 0.f, 0.f};
            accL[i][j] = (f32x4){0.f, 0.f, 0.f, 0.f};
        }
    #pragma unroll
    for (int ks = 0; ks < 2; ks++) {
        short8 pf[4], vt[4], kt[4];
        #pragma unroll
        for (int i = 0; i < 4; i++) {
            int row = i * 16 + fl;
            int koff = (((ks * 4 + kb) ^ (row & 7) ^ (row >> 3))) << 3;
            pf[i] = *(const short8*)(Ps  + row * 64 + koff);
            vt[i] = *(const short8*)(VTs + row * 64 + koff);
            kt[i] = *(const short8*)(KTs + row * 64 + koff);
        }
        #pragma unroll
        for (int i = 0; i < 4; i++)
            #pragma unroll
            for (int j = 0; j < 4; j++) {
                accO[i][j] = __builtin_amdgcn_mfma_f32_16x16x32_bf16(pf[i], vt[j], accO[i][j], 0, 0, 0);
                accL[i][j] = __builtin_amdgcn_mfma_f32_16x16x32_bf16(vt[i], kt[j], accL[i][j], 0, 0, 0);
            }
    }

    #pragma unroll
    for (int i = 0; i < 4; i++)
        #pragma unroll
        for (int j = 0; j < 4; j++)
            #pragma unroll
            for (int r = 0; r < 4; r++) {
                int rr = i * 16 + kb * 4 + r, cc2 = j * 16 + fl;
                attb[(rowBase + rr) * (Hq * Dq) + hh * Dq + cc2] = f2b(accO[i][j][r]);
                LT[(size_t)blk * 4096 + rr * 64 + cc2] = f2b(accL[i][j][r]);
            }
}

// ---------------- pass2: cross-chunk combine (elementwise, LT layout [e][d]) ----------------
__global__ __launch_bounds__(256) void scan_pass2(bf16* __restrict__ LH,
                                                  const float* __restrict__ Fchunk,
                                                  const float* __restrict__ h0,
                                                  float* __restrict__ hfin) {
    int idx = blockIdx.x * 256 + threadIdx.x;   // over BH*4096 in [e][d] order
    int bh = idx >> 12;
    int ed = idx & 4095;
    int e = ed >> 6, d = ed & 63;
    float run = h0[(size_t)bh * 4096 + d * 64 + e];   // seed with initial state
    #pragma unroll
    for (int c = 0; c < Cc; c++) {
        float Fv = Fchunk[bh * Cc + c];
        size_t off = ((size_t)bh * Cc + c) * 4096 + ed;
        float Lv = b2f(LH[off]);
        LH[off] = f2b(run);          // Hstart_c (transposed layout)
        run = Fv * run + Lv;
    }
    hfin[(size_t)bh * 4096 + d * 64 + e] = run;
}

// ---------------- chunk kernel B: cross-chunk contribution ----------------
// att[t][e] += oa_t * sum_d Q[t][d] * Hstart[d][e]   (HT rows are e, cols d)
__global__ __launch_bounds__(64) void chunk_cross(const bf16* __restrict__ qkvb,
                                                  const bf16* __restrict__ HT,
                                                  const float* __restrict__ oaArr,
                                                  bf16* __restrict__ attb) {
    const int blk = blockIdx.x;
    const int c = blk & (Cc - 1);
    const int bh = blk >> 5;
    const int b = bh >> 4, hh = bh & 15;
    const int l = threadIdx.x, fl = l & 15, kb = l >> 4;
    const size_t rowBase = (size_t)(b * Sq + c * Tc);
    __shared__ float oaS[64];
    oaS[l] = oaArr[(size_t)blk * 64 + l];
    __syncthreads();
    const bf16* Qb = qkvb + rowBase * QKVW + hh * Dq;
    const bf16* Hb = HT + (size_t)blk * 4096;
    f32x4 acc[4][4];
    #pragma unroll
    for (int i = 0; i < 4; i++)
        #pragma unroll
        for (int j = 0; j < 4; j++) acc[i][j] = (f32x4){0.f, 0.f, 0.f, 0.f};
    #pragma unroll
    for (int ks = 0; ks < 2; ks++) {
        short8 qf[4], hf[4];
        #pragma unroll
        for (int i = 0; i < 4; i++)
            qf[i] = *(const short8*)(Qb + (size_t)(i * 16 + fl) * QKVW + ks * 32 + kb * 8);
        #pragma unroll
        for (int j = 0; j < 4; j++)
            hf[j] = *(const short8*)(Hb + (j * 16 + fl) * 64 + ks * 32 + kb * 8);
        #pragma unroll
        for (int i = 0; i < 4; i++)
            #pragma unroll
            for (int j = 0; j < 4; j++)
                acc[i][j] = __builtin_amdgcn_mfma_f32_16x16x32_bf16(qf[i], hf[j], acc[i][j], 0, 0, 0);
    }
    #pragma unroll
    for (int i = 0; i < 4; i++)
        #pragma unroll
        for (int j = 0; j < 4; j++)
            #pragma unroll
            for (int r = 0; r < 4; r++) {
                int t = i * 16 + kb * 4 + r, e = j * 16 + fl;
                size_t idx = (rowBase + t) * (Hq * Dq) + hh * Dq + e;
                attb[idx] = f2b(b2f(attb[idx]) + oaS[t] * acc[i][j][r]);
            }
}

extern "C" void kernel_launch(void* const* d_in, const int* in_sizes, int n_in,
                              void* d_out, int out_size, void* d_ws, size_t ws_size,
                              hipStream_t stream) {
    const float* x      = (const float*)d_in[0];
    const float* h0     = (const float*)d_in[1];
    const float* w_qkv  = (const float*)d_in[2];
    const float* w_gate = (const float*)d_in[3];
    const float* w_out  = (const float*)d_in[4];
    const float* ln_w   = (const float*)d_in[5];

    const size_t MS = (size_t)Bq * Sq;            // 8192
    const size_t BH = (size_t)Bq * Hq;            // 64

    float* p = (float*)d_ws;
    bf16*  xnb   = (bf16*)p;  p += MS * DMq / 2;                 // 4.19M
    bf16*  qkvb  = (bf16*)p;  p += MS * QKVW / 2;                // 12.58M
    float* gates = p;         p += MS * 3 * Hq;                  // 393K
    float* oaArr = p;         p += BH * Cc * Tc;                 // 131K
    float* Fch   = p;         p += BH * Cc;                      // 2K
    bf16*  LT    = (bf16*)p;  p += BH * Cc * Dq * Dq / 2;        // 4.19M
    bf16*  wqb   = (bf16*)p;  p += (size_t)QKVW * DMq / 2;       // 1.57M
    bf16*  wgb   = (bf16*)p;  p += (size_t)3 * Hq * DMq / 2;
    bf16*  wob   = (bf16*)p;  p += (size_t)DMq * Hq * Dq / 2;
    size_t need = (size_t)(p - (float*)d_ws) * sizeof(float);
    if (ws_size < need) return;
    bf16* attb = xnb;   // alias: xnb dead after QKV+gates GEMMs

    float* y    = (float*)d_out;
    float* hfin = y + MS * DMq;

    convert_f32_bf16<<<dim3(3072), dim3(256), 0, stream>>>(w_qkv, wqb, QKVW * DMq / 4);
    convert_f32_bf16<<<dim3(48),   dim3(256), 0, stream>>>(w_gate, wgb, 3 * Hq * DMq / 4);
    convert_f32_bf16<<<dim3(1024), dim3(256), 0, stream>>>(w_out, wob, DMq * Hq * Dq / 4);

    rmsnorm_kernel<<<dim3(MS), dim3(256), 0, stream>>>(x, ln_w, xnb);

    gemm_mfma<EPI_BF16><<<dim3(QKVW / 128, MS / 128), dim3(256), 0, stream>>>(
        xnb, wqb, nullptr, qkvb, (int)MS, QKVW, DMq);

    gemm_mfma<EPI_GATE><<<dim3(1, MS / 128), dim3(256), 0, stream>>>(
        xnb, wgb, nullptr, gates, (int)MS, 3 * Hq, DMq);

    chunk_intra<<<dim3(BH * Cc), dim3(64), 0, stream>>>(qkvb, gates, attb, LT, oaArr, Fch);
    scan_pass2<<<dim3(BH * 4096 / 256), dim3(256), 0, stream>>>(LT, Fch, h0, hfin);
    chunk_cross<<<dim3(BH * Cc), dim3(64), 0, stream>>>(qkvb, LT, oaArr, attb);

    gemm_mfma<EPI_RESID><<<dim3(DMq / 128, MS / 128), dim3(256), 0, stream>>>(
        attb, wob, x, y, (int)MS, DMq, Hq * Dq);
}